// Round 4
// baseline (2373.604 us; speedup 1.0000x reference)
//
#include <hip/hip_runtime.h>

// PoissonPinn, round-7: round-6 structure with the SK bug fixed.
//
// Round-6 failed correctness: SK=252 < 256 columns — k runs 0..255, so cols
// 252..255 of each LDS row aliased cols 0..3 of the next row (absmax 1.6e-2).
// Round-7:
//  * SK = 256 exactly (no pad; 6*16*256*2 = 49152 B = 48 KiB). Bank conflicts
//    from the 512B row stride are killed by an XOR swizzle on 8B blocks:
//    col' = col ^ (row<<2). Audit: per q-group the block index is constant and
//    XOR row spreads 16 rows over 16 bank-pairs; cross-q collisions need
//    m1^m2 = q1^q2 -> exactly 4 lanes/bank-pair = wave64 minimum. Conflict-free.
//  * red[] scratch aliases Hls (Hls is dead by then; extra barrier guards it),
//    so LDS block = 49152 -> 3 blocks/CU even at 16K granule.
//  * Keeps round-6: transition interleave (drain barrier before epilogue,
//    storeP + own-chunk mfma9s mixed into epilogue halves), fused boundary
//    blocks, __launch_bounds__(256,3).

constexpr int HID   = 256;
constexpr int MPTS  = 16;              // points per eq block
constexpr int SK    = 256;             // LDS row stride in bf16 elems (512B)
constexpr int WELEM = 3 * HID * HID;
constexpr int HLSB  = 6 * MPTS * SK * 2;   // 49152 B = 48 KiB

typedef __bf16 bf16x8 __attribute__((ext_vector_type(8)));
typedef __bf16 bf16x4 __attribute__((ext_vector_type(4)));
typedef float  f32x4  __attribute__((ext_vector_type(4)));

__device__ __forceinline__ float fast_tanh(float x) {
    float e = __expf(2.0f * x);
    return 1.0f - 2.0f / (e + 1.0f);
}

// ---- prep: W1..W3 (fp32 [k][n]) -> bf16 hi/lo, A-fragment order.
// Layout Wf[l][NT(16)][ks(8)][lane(64)][j(8)]: lane = q*16+m supplies
// A[n = NT*16+m][slot j] = W[k][n] with k = 32*ks + 16*(j>>2) + 4*q + (j&3).
__global__ void prep_w(const float* __restrict__ W1,
                       const float* __restrict__ W2,
                       const float* __restrict__ W3,
                       __bf16* __restrict__ Wh, __bf16* __restrict__ Wl) {
    const int idx = blockIdx.x * 256 + threadIdx.x;   // 0 .. WELEM-1
    const int l   = idx >> 16;
    const int r   = idx & 0xFFFF;
    const int NT  = r >> 12;
    const int ks  = (r >> 9) & 7;
    const int ln  = (r >> 3) & 63;
    const int j   = r & 7;
    const int q   = ln >> 4;
    const int mm  = ln & 15;
    const int k   = ks * 32 + ((j >> 2) << 4) + q * 4 + (j & 3);
    const int n   = NT * 16 + mm;
    const float* W = (l == 0) ? W1 : (l == 1) ? W2 : W3;
    const float w  = W[k * HID + n];
    const __bf16 hi = (__bf16)w;
    Wh[idx] = hi;
    Wl[idx] = (__bf16)(w - (float)hi);
}

__global__ __launch_bounds__(256, 3)
void pinn_fused(const float* __restrict__ xe, const float* __restrict__ xb,
                const float* __restrict__ W0, const float* __restrict__ b0,
                const float* __restrict__ b1, const float* __restrict__ b2,
                const float* __restrict__ b3, const float* __restrict__ W4,
                const float* __restrict__ b4,
                const float* __restrict__ W1f, const float* __restrict__ W2f,
                const float* __restrict__ W3f,
                const __bf16* __restrict__ Wh, const __bf16* __restrict__ Wl,
                float* __restrict__ out, int neqb, int n_eq)
{
    __shared__ __align__(16) unsigned char smem[HLSB];   // 49152 B

    const int tid  = threadIdx.x;
    const int lane = tid & 63;
    const int wv   = tid >> 6;

    if ((int)blockIdx.x >= neqb) {
        // ================= boundary path (fp32 vector forward) =============
        float (*HV)[HID] = (float (*)[HID])smem;
        const int rbase = wv * 4;
        const int pbase = ((int)blockIdx.x - neqb) * 16 + rbase;
        float* bout = out + n_eq;

        #pragma unroll
        for (int c = 0; c < 4; ++c) {
            const int   j  = lane + 64 * c;
            const float w  = W0[j];
            const float bb = b0[j];
            #pragma unroll
            for (int p = 0; p < 4; ++p)
                HV[rbase + p][j] = fast_tanh(xb[pbase + p] * w + bb);
        }
        __syncthreads();

        const float* Ws[3] = {W1f, W2f, W3f};
        const float* bs[3] = {b1, b2, b3};

        #pragma unroll
        for (int l = 0; l < 3; ++l) {
            const float* __restrict__ W = Ws[l];
            const float* __restrict__ b = bs[l];

            float zv[4][4];
            #pragma unroll
            for (int p = 0; p < 4; ++p)
                #pragma unroll
                for (int c = 0; c < 4; ++c)
                    zv[p][c] = b[lane + 64 * c];

            for (int i = 0; i < HID; i += 4) {
                float w[4][4];
                #pragma unroll
                for (int qq = 0; qq < 4; ++qq)
                    #pragma unroll
                    for (int c = 0; c < 4; ++c)
                        w[qq][c] = W[(i + qq) * HID + lane + 64 * c];

                #pragma unroll
                for (int p = 0; p < 4; ++p) {
                    const float4 av = *(const float4*)&HV[rbase + p][i];
                    #pragma unroll
                    for (int qq = 0; qq < 4; ++qq) {
                        const float a_v = ((const float*)&av)[qq];
                        #pragma unroll
                        for (int c = 0; c < 4; ++c)
                            zv[p][c] = fmaf(a_v, w[qq][c], zv[p][c]);
                    }
                }
            }
            __syncthreads();

            #pragma unroll
            for (int p = 0; p < 4; ++p)
                #pragma unroll
                for (int c = 0; c < 4; ++c)
                    HV[rbase + p][lane + 64 * c] = fast_tanh(zv[p][c]);
            __syncthreads();
        }

        const float bias4 = b4[0];
        #pragma unroll
        for (int p = 0; p < 4; ++p) {
            float acc = 0.0f;
            #pragma unroll
            for (int c = 0; c < 4; ++c) {
                const int j = lane + 64 * c;
                acc = fmaf(HV[rbase + p][j], W4[j], acc);
            }
            #pragma unroll
            for (int off = 32; off > 0; off >>= 1)
                acc += __shfl_down(acc, off, 64);
            if (lane == 0) bout[pbase + p] = acc + bias4;
        }
        return;
    }

    // ================= equation path (2nd-order jet, MFMA) =================
    typedef __bf16 (*HlsT)[MPTS][SK];
    HlsT Hls = (HlsT)smem;                               // [6][16][256]
    float (*red)[16] = (float (*)[16])smem;              // ALIASES Hls (guarded)

    const int m    = lane & 15;     // = p (output col / B-frag col)
    const int q    = lane >> 4;
    const int pb   = blockIdx.x * MPTS;

    f32x4 acc[3][4];                               // [ch][nt]
    bf16x8 AH0[4], AL0[4], AH1[4], AL1[4];         // weight frags (dbuf)
    bf16x8 BH0[3], BL0[3], BH1[3], BL1[3];         // activation frags (dbuf)

    auto zacc = [&]() {
        #pragma unroll
        for (int ch = 0; ch < 3; ++ch)
            #pragma unroll
            for (int nt = 0; nt < 4; ++nt)
                acc[ch][nt] = (f32x4)0.0f;
    };
    auto loadA = [&](bf16x8 (&AH)[4], bf16x8 (&AL)[4],
                     const __bf16* wh, const __bf16* wl, int ks) {
        #pragma unroll
        for (int nt = 0; nt < 4; ++nt) {
            const int off = (((wv * 4 + nt) * 8 + ks) * 64 + lane) * 8;
            AH[nt] = *(const bf16x8*)(wh + off);
            AL[nt] = *(const bf16x8*)(wl + off);
        }
    };
    // XOR swizzle: col' = col ^ (row<<2), 8B-block granular, bijective in-row.
    auto loadB = [&](bf16x8 (&BH)[3], bf16x8 (&BL)[3], int ks) {
        const int sw  = m << 2;
        const int kb0 = (ks * 32 + q * 4) ^ sw;
        const int kb1 = (ks * 32 + q * 4 + 16) ^ sw;
        #pragma unroll
        for (int ch = 0; ch < 3; ++ch) {
            const bf16x4 h0 = *(const bf16x4*)&Hls[ch * 2    ][m][kb0];
            const bf16x4 h1 = *(const bf16x4*)&Hls[ch * 2    ][m][kb1];
            const bf16x4 l0 = *(const bf16x4*)&Hls[ch * 2 + 1][m][kb0];
            const bf16x4 l1 = *(const bf16x4*)&Hls[ch * 2 + 1][m][kb1];
            BH[ch] = __builtin_shufflevector(h0, h1, 0, 1, 2, 3, 4, 5, 6, 7);
            BL[ch] = __builtin_shufflevector(l0, l1, 0, 1, 2, 3, 4, 5, 6, 7);
        }
    };
    auto mfma36 = [&](const bf16x8 (&AH)[4], const bf16x8 (&AL)[4],
                      const bf16x8 (&BH)[3], const bf16x8 (&BL)[3]) {
        __builtin_amdgcn_s_setprio(1);
        #pragma unroll
        for (int ch = 0; ch < 3; ++ch)
            #pragma unroll
            for (int nt = 0; nt < 4; ++nt)
                acc[ch][nt] = __builtin_amdgcn_mfma_f32_16x16x32_bf16(AH[nt], BH[ch], acc[ch][nt], 0, 0, 0);
        #pragma unroll
        for (int ch = 0; ch < 3; ++ch)
            #pragma unroll
            for (int nt = 0; nt < 4; ++nt)
                acc[ch][nt] = __builtin_amdgcn_mfma_f32_16x16x32_bf16(AH[nt], BL[ch], acc[ch][nt], 0, 0, 0);
        #pragma unroll
        for (int ch = 0; ch < 3; ++ch)
            #pragma unroll
            for (int nt = 0; nt < 4; ++nt)
                acc[ch][nt] = __builtin_amdgcn_mfma_f32_16x16x32_bf16(AL[nt], BH[ch], acc[ch][nt], 0, 0, 0);
        __builtin_amdgcn_s_setprio(0);
    };
    // 9 MFMAs: one A-frag x 3 channels x 3 split terms; no setprio (we WANT
    // VALU interleave in the transition).
    auto mfma9 = [&](const bf16x8& aH, const bf16x8& aL,
                     const bf16x8 (&bh)[3], const bf16x8 (&bl)[3],
                     f32x4& c0, f32x4& c1, f32x4& c2) {
        c0 = __builtin_amdgcn_mfma_f32_16x16x32_bf16(aH, bh[0], c0, 0, 0, 0);
        c1 = __builtin_amdgcn_mfma_f32_16x16x32_bf16(aH, bh[1], c1, 0, 0, 0);
        c2 = __builtin_amdgcn_mfma_f32_16x16x32_bf16(aH, bh[2], c2, 0, 0, 0);
        c0 = __builtin_amdgcn_mfma_f32_16x16x32_bf16(aH, bl[0], c0, 0, 0, 0);
        c1 = __builtin_amdgcn_mfma_f32_16x16x32_bf16(aH, bl[1], c1, 0, 0, 0);
        c2 = __builtin_amdgcn_mfma_f32_16x16x32_bf16(aH, bl[2], c2, 0, 0, 0);
        c0 = __builtin_amdgcn_mfma_f32_16x16x32_bf16(aL, bh[0], c0, 0, 0, 0);
        c1 = __builtin_amdgcn_mfma_f32_16x16x32_bf16(aL, bh[1], c1, 0, 0, 0);
        c2 = __builtin_amdgcn_mfma_f32_16x16x32_bf16(aL, bh[2], c2, 0, 0, 0);
    };
    auto storeP = [&](const bf16x8 (&PH)[3], const bf16x8 (&PL)[3], int c) {
        const int sw = m << 2;
        const int k0 = (wv * 64 + c * 32 + q * 4) ^ sw;
        const int k1 = (wv * 64 + c * 32 + q * 4 + 16) ^ sw;
        #pragma unroll
        for (int ch = 0; ch < 3; ++ch) {
            *(bf16x4*)&Hls[ch * 2    ][m][k0] = __builtin_shufflevector(PH[ch], PH[ch], 0, 1, 2, 3);
            *(bf16x4*)&Hls[ch * 2 + 1][m][k0] = __builtin_shufflevector(PL[ch], PL[ch], 0, 1, 2, 3);
            *(bf16x4*)&Hls[ch * 2    ][m][k1] = __builtin_shufflevector(PH[ch], PH[ch], 4, 5, 6, 7);
            *(bf16x4*)&Hls[ch * 2 + 1][m][k1] = __builtin_shufflevector(PL[ch], PL[ch], 4, 5, 6, 7);
        }
    };

    // ---- layer 0: thread -> point p = tid&15, cols cg..cg+15 ----
    {
        const int p  = tid & 15;
        const int cg = (tid >> 4) * 16;
        const float xv = xe[pb + p];
        float vv[16], dd[16], ss[16];
        #pragma unroll
        for (int cc = 0; cc < 16; ++cc) {
            const int c = cg + cc;
            const float w  = W0[c];
            const float bb = b0[c];
            const float v  = fast_tanh(fmaf(xv, w, bb));
            const float s2 = 1.0f - v * v;
            vv[cc] = v;
            dd[cc] = s2 * w;
            ss[cc] = -2.0f * v * s2 * w * w;
        }
        auto packwrite = [&](const float (&a)[16], int cp) {
            #pragma unroll
            for (int g = 0; g < 4; ++g) {
                bf16x4 h, lo;
                #pragma unroll
                for (int e = 0; e < 4; ++e) {
                    const float fv = a[g * 4 + e];
                    const __bf16 hh = (__bf16)fv;
                    h[e]  = hh;
                    lo[e] = (__bf16)(fv - (float)hh);
                }
                const int col = (cg + g * 4) ^ (p << 2);
                *(bf16x4*)&Hls[cp    ][p][col] = h;
                *(bf16x4*)&Hls[cp + 1][p][col] = lo;
            }
        };
        packwrite(vv, 0);
        packwrite(dd, 2);
        packwrite(ss, 4);
    }
    __syncthreads();

    // ---- GEMM layer 1 (W1): all 8 K-chunks from LDS, dbuf pipeline ----
    zacc();
    loadA(AH0, AL0, Wh, Wl, 0);
    loadB(BH0, BL0, 0);
    #pragma unroll 1
    for (int it = 0; it < 4; ++it) {
        const int ks = it * 2;
        loadA(AH1, AL1, Wh, Wl, ks + 1);
        loadB(BH1, BL1, ks + 1);
        mfma36(AH0, AL0, BH0, BL0);
        if (it < 3) {
            loadA(AH0, AL0, Wh, Wl, ks + 2);
            loadB(BH0, BL0, ks + 2);
        }
        mfma36(AH1, AL1, BH1, BL1);
    }

    // ---- transitions: drain -> (epi c0 | store | own-mfma) x2 -> publish ----
    #pragma unroll 1
    for (int l = 0; l < 2; ++l) {
        const __bf16* whN = Wh + (l + 1) * (HID * HID);
        const __bf16* wlN = Wl + (l + 1) * (HID * HID);
        const float* bl = (l == 0) ? b1 : b2;

        __syncthreads();   // read-drain: all waves done reading H(l)
        loadA(AH0, AL0, whN, wlN, 2 * wv);         // own-chunk A frags (L2)
        loadA(AH1, AL1, whN, wlN, 2 * wv + 1);

        bf16x8 P0H[3], P0L[3], P1H[3], P1L[3];

        // ---- epilogue half c = 0 (nt 0,1) ----
        #pragma unroll
        for (int t = 0; t < 2; ++t)
            #pragma unroll
            for (int r = 0; r < 4; ++r) {
                const int nt = t;
                const int n  = (wv * 4 + nt) * 16 + q * 4 + r;
                const float zv = acc[0][nt][r] + bl[n];
                const float zd = acc[1][nt][r];
                const float zs = acc[2][nt][r];
                const float v  = fast_tanh(zv);
                const float s2 = 1.0f - v * v;
                const float dn = s2 * zd;
                const float sn = s2 * zs - 2.0f * v * s2 * zd * zd;
                const int e = t * 4 + r;
                { const __bf16 h = (__bf16)v;  P0H[0][e] = h; P0L[0][e] = (__bf16)(v  - (float)h); }
                { const __bf16 h = (__bf16)dn; P0H[1][e] = h; P0L[1][e] = (__bf16)(dn - (float)h); }
                { const __bf16 h = (__bf16)sn; P0H[2][e] = h; P0L[2][e] = (__bf16)(sn - (float)h); }
            }
        storeP(P0H, P0L, 0);                       // DS pipe, overlaps c=1 VALU
        #pragma unroll
        for (int ch = 0; ch < 3; ++ch) { acc[ch][0] = (f32x4)0.0f; acc[ch][1] = (f32x4)0.0f; }
        mfma9(AH0[0], AL0[0], P0H, P0L, acc[0][0], acc[1][0], acc[2][0]);   // own chunk 2wv, nt0
        mfma9(AH0[1], AL0[1], P0H, P0L, acc[0][1], acc[1][1], acc[2][1]);   // own chunk 2wv, nt1

        // ---- epilogue half c = 1 (nt 2,3) — interleaves with MFMAs above ----
        #pragma unroll
        for (int t = 0; t < 2; ++t)
            #pragma unroll
            for (int r = 0; r < 4; ++r) {
                const int nt = 2 + t;
                const int n  = (wv * 4 + nt) * 16 + q * 4 + r;
                const float zv = acc[0][nt][r] + bl[n];
                const float zd = acc[1][nt][r];
                const float zs = acc[2][nt][r];
                const float v  = fast_tanh(zv);
                const float s2 = 1.0f - v * v;
                const float dn = s2 * zd;
                const float sn = s2 * zs - 2.0f * v * s2 * zd * zd;
                const int e = t * 4 + r;
                { const __bf16 h = (__bf16)v;  P1H[0][e] = h; P1L[0][e] = (__bf16)(v  - (float)h); }
                { const __bf16 h = (__bf16)dn; P1H[1][e] = h; P1L[1][e] = (__bf16)(dn - (float)h); }
                { const __bf16 h = (__bf16)sn; P1H[2][e] = h; P1L[2][e] = (__bf16)(sn - (float)h); }
            }
        storeP(P1H, P1L, 1);
        #pragma unroll
        for (int ch = 0; ch < 3; ++ch) { acc[ch][2] = (f32x4)0.0f; acc[ch][3] = (f32x4)0.0f; }
        mfma9(AH0[2], AL0[2], P0H, P0L, acc[0][2], acc[1][2], acc[2][2]);   // own chunk 2wv, nt2
        mfma9(AH0[3], AL0[3], P0H, P0L, acc[0][3], acc[1][3], acc[2][3]);   // own chunk 2wv, nt3
        mfma9(AH1[0], AL1[0], P1H, P1L, acc[0][0], acc[1][0], acc[2][0]);   // own chunk 2wv+1
        mfma9(AH1[1], AL1[1], P1H, P1L, acc[0][1], acc[1][1], acc[2][1]);
        mfma9(AH1[2], AL1[2], P1H, P1L, acc[0][2], acc[1][2], acc[2][2]);
        mfma9(AH1[3], AL1[3], P1H, P1L, acc[0][3], acc[1][3], acc[2][3]);

        loadA(AH0, AL0, whN, wlN, (2 * wv + 2) & 7);   // prefetch first LDS chunk's A
        __syncthreads();   // publish H(l+1)
        loadB(BH0, BL0, (2 * wv + 2) & 7);
        #pragma unroll 1
        for (int it = 0; it < 3; ++it) {
            const int kb = (2 * wv + 3 + 2 * it) & 7;
            loadA(AH1, AL1, whN, wlN, kb);
            loadB(BH1, BL1, kb);
            mfma36(AH0, AL0, BH0, BL0);
            if (it < 2) {
                const int kc = (2 * wv + 4 + 2 * it) & 7;
                loadA(AH0, AL0, whN, wlN, kc);
                loadB(BH0, BL0, kc);
            }
            mfma36(AH1, AL1, BH1, BL1);
        }
    }

    // ---- layer 3 finish: s-channel register-direct into W4 dot ----
    {
        float P = 0.0f;
        #pragma unroll
        for (int nt = 0; nt < 4; ++nt)
            #pragma unroll
            for (int r = 0; r < 4; ++r) {
                const int n  = (wv * 4 + nt) * 16 + q * 4 + r;
                const float zv = acc[0][nt][r] + b3[n];
                const float zd = acc[1][nt][r];
                const float zs = acc[2][nt][r];
                const float v  = fast_tanh(zv);
                const float s2 = 1.0f - v * v;
                const float sn = s2 * zs - 2.0f * v * s2 * zd * zd;
                P = fmaf(sn, W4[n], P);
            }
        P += __shfl_xor(P, 16, 64);
        P += __shfl_xor(P, 32, 64);
        __syncthreads();   // all Hls reads done everywhere; red may alias Hls
        if (q == 0) red[wv][m] = P;
        __syncthreads();
        if (tid < 16)
            out[pb + tid] = red[0][tid] + red[1][tid] + red[2][tid] + red[3][tid];
    }
}

extern "C" void kernel_launch(void* const* d_in, const int* in_sizes, int n_in,
                              void* d_out, int out_size, void* d_ws, size_t ws_size,
                              hipStream_t stream) {
    const float* xe = (const float*)d_in[0];
    const float* xb = (const float*)d_in[1];
    const float* W0 = (const float*)d_in[2];
    const float* b0 = (const float*)d_in[3];
    const float* W1 = (const float*)d_in[4];
    const float* b1 = (const float*)d_in[5];
    const float* W2 = (const float*)d_in[6];
    const float* b2 = (const float*)d_in[7];
    const float* W3 = (const float*)d_in[8];
    const float* b3 = (const float*)d_in[9];
    const float* W4 = (const float*)d_in[10];
    const float* b4 = (const float*)d_in[11];
    float* out = (float*)d_out;

    const int n_eq = in_sizes[0];   // 262144
    const int n_b  = in_sizes[1];   // 8192

    __bf16* Wh = (__bf16*)d_ws;                    // 3*256*256 bf16
    __bf16* Wl = Wh + WELEM;

    const int neqb = n_eq / MPTS;                  // 16384
    const int nbb  = n_b / 16;                     // 512

    prep_w<<<WELEM / 256, 256, 0, stream>>>(W1, W2, W3, Wh, Wl);

    pinn_fused<<<neqb + nbb, 256, 0, stream>>>(
        xe, xb, W0, b0, b1, b2, b3, W4, b4, W1, W2, W3, Wh, Wl, out, neqb, n_eq);
}

// Round 5
// 999.103 us; speedup vs baseline: 2.3757x; 2.3757x over previous
//
#include <hip/hip_runtime.h>

// PoissonPinn, round-8: round-7 structure at the correct occupancy bound.
//
// Round-7 post-mortem: __launch_bounds__(256,3) -> unified file split gave
// 84 arch VGPRs/wave; the ~180-reg working set spilled to scratch (9.3 GB
// HBM traffic/dispatch, MfmaUtil 16%, dur 2.4ms). This kernel's working set
// pins occupancy at 2 blocks/CU — same conclusion as the inherited round-3.
//
// Round-8 keeps round-7's verified-correct improvements at (256,2):
//  * SK=256, XOR swizzle col^=(row<<2) on 8B blocks (bank conflicts = 0).
//  * Transition interleave: drain barrier BEFORE epilogue; storeP (DS pipe)
//    and own-chunk mfma9s (MFMA pipe) mixed between the epilogue's two
//    independent VALU halves.
//  * Boundary network fused as tail blocks of the same grid.
//  * red[] aliases Hls (guarded by a barrier), LDS = 48 KiB exactly.

constexpr int HID   = 256;
constexpr int MPTS  = 16;              // points per eq block
constexpr int SK    = 256;             // LDS row stride in bf16 elems (512B)
constexpr int WELEM = 3 * HID * HID;
constexpr int HLSB  = 6 * MPTS * SK * 2;   // 49152 B = 48 KiB

typedef __bf16 bf16x8 __attribute__((ext_vector_type(8)));
typedef __bf16 bf16x4 __attribute__((ext_vector_type(4)));
typedef float  f32x4  __attribute__((ext_vector_type(4)));

__device__ __forceinline__ float fast_tanh(float x) {
    float e = __expf(2.0f * x);
    return 1.0f - 2.0f / (e + 1.0f);
}

// ---- prep: W1..W3 (fp32 [k][n]) -> bf16 hi/lo, A-fragment order.
// Layout Wf[l][NT(16)][ks(8)][lane(64)][j(8)]: lane = q*16+m supplies
// A[n = NT*16+m][slot j] = W[k][n] with k = 32*ks + 16*(j>>2) + 4*q + (j&3).
__global__ void prep_w(const float* __restrict__ W1,
                       const float* __restrict__ W2,
                       const float* __restrict__ W3,
                       __bf16* __restrict__ Wh, __bf16* __restrict__ Wl) {
    const int idx = blockIdx.x * 256 + threadIdx.x;   // 0 .. WELEM-1
    const int l   = idx >> 16;
    const int r   = idx & 0xFFFF;
    const int NT  = r >> 12;
    const int ks  = (r >> 9) & 7;
    const int ln  = (r >> 3) & 63;
    const int j   = r & 7;
    const int q   = ln >> 4;
    const int mm  = ln & 15;
    const int k   = ks * 32 + ((j >> 2) << 4) + q * 4 + (j & 3);
    const int n   = NT * 16 + mm;
    const float* W = (l == 0) ? W1 : (l == 1) ? W2 : W3;
    const float w  = W[k * HID + n];
    const __bf16 hi = (__bf16)w;
    Wh[idx] = hi;
    Wl[idx] = (__bf16)(w - (float)hi);
}

__global__ __launch_bounds__(256, 2)
void pinn_fused(const float* __restrict__ xe, const float* __restrict__ xb,
                const float* __restrict__ W0, const float* __restrict__ b0,
                const float* __restrict__ b1, const float* __restrict__ b2,
                const float* __restrict__ b3, const float* __restrict__ W4,
                const float* __restrict__ b4,
                const float* __restrict__ W1f, const float* __restrict__ W2f,
                const float* __restrict__ W3f,
                const __bf16* __restrict__ Wh, const __bf16* __restrict__ Wl,
                float* __restrict__ out, int neqb, int n_eq)
{
    __shared__ __align__(16) unsigned char smem[HLSB];   // 49152 B

    const int tid  = threadIdx.x;
    const int lane = tid & 63;
    const int wv   = tid >> 6;

    if ((int)blockIdx.x >= neqb) {
        // ================= boundary path (fp32 vector forward) =============
        float (*HV)[HID] = (float (*)[HID])smem;
        const int rbase = wv * 4;
        const int pbase = ((int)blockIdx.x - neqb) * 16 + rbase;
        float* bout = out + n_eq;

        #pragma unroll
        for (int c = 0; c < 4; ++c) {
            const int   j  = lane + 64 * c;
            const float w  = W0[j];
            const float bb = b0[j];
            #pragma unroll
            for (int p = 0; p < 4; ++p)
                HV[rbase + p][j] = fast_tanh(xb[pbase + p] * w + bb);
        }
        __syncthreads();

        const float* Ws[3] = {W1f, W2f, W3f};
        const float* bs[3] = {b1, b2, b3};

        #pragma unroll
        for (int l = 0; l < 3; ++l) {
            const float* __restrict__ W = Ws[l];
            const float* __restrict__ b = bs[l];

            float zv[4][4];
            #pragma unroll
            for (int p = 0; p < 4; ++p)
                #pragma unroll
                for (int c = 0; c < 4; ++c)
                    zv[p][c] = b[lane + 64 * c];

            for (int i = 0; i < HID; i += 4) {
                float w[4][4];
                #pragma unroll
                for (int qq = 0; qq < 4; ++qq)
                    #pragma unroll
                    for (int c = 0; c < 4; ++c)
                        w[qq][c] = W[(i + qq) * HID + lane + 64 * c];

                #pragma unroll
                for (int p = 0; p < 4; ++p) {
                    const float4 av = *(const float4*)&HV[rbase + p][i];
                    #pragma unroll
                    for (int qq = 0; qq < 4; ++qq) {
                        const float a_v = ((const float*)&av)[qq];
                        #pragma unroll
                        for (int c = 0; c < 4; ++c)
                            zv[p][c] = fmaf(a_v, w[qq][c], zv[p][c]);
                    }
                }
            }
            __syncthreads();

            #pragma unroll
            for (int p = 0; p < 4; ++p)
                #pragma unroll
                for (int c = 0; c < 4; ++c)
                    HV[rbase + p][lane + 64 * c] = fast_tanh(zv[p][c]);
            __syncthreads();
        }

        const float bias4 = b4[0];
        #pragma unroll
        for (int p = 0; p < 4; ++p) {
            float acc = 0.0f;
            #pragma unroll
            for (int c = 0; c < 4; ++c) {
                const int j = lane + 64 * c;
                acc = fmaf(HV[rbase + p][j], W4[j], acc);
            }
            #pragma unroll
            for (int off = 32; off > 0; off >>= 1)
                acc += __shfl_down(acc, off, 64);
            if (lane == 0) bout[pbase + p] = acc + bias4;
        }
        return;
    }

    // ================= equation path (2nd-order jet, MFMA) =================
    typedef __bf16 (*HlsT)[MPTS][SK];
    HlsT Hls = (HlsT)smem;                               // [6][16][256]
    float (*red)[16] = (float (*)[16])smem;              // ALIASES Hls (guarded)

    const int m    = lane & 15;     // = p (output col / B-frag col)
    const int q    = lane >> 4;
    const int pb   = blockIdx.x * MPTS;

    f32x4 acc[3][4];                               // [ch][nt]
    bf16x8 AH0[4], AL0[4], AH1[4], AL1[4];         // weight frags (dbuf)
    bf16x8 BH0[3], BL0[3], BH1[3], BL1[3];         // activation frags (dbuf)

    auto zacc = [&]() {
        #pragma unroll
        for (int ch = 0; ch < 3; ++ch)
            #pragma unroll
            for (int nt = 0; nt < 4; ++nt)
                acc[ch][nt] = (f32x4)0.0f;
    };
    auto loadA = [&](bf16x8 (&AH)[4], bf16x8 (&AL)[4],
                     const __bf16* wh, const __bf16* wl, int ks) {
        #pragma unroll
        for (int nt = 0; nt < 4; ++nt) {
            const int off = (((wv * 4 + nt) * 8 + ks) * 64 + lane) * 8;
            AH[nt] = *(const bf16x8*)(wh + off);
            AL[nt] = *(const bf16x8*)(wl + off);
        }
    };
    // XOR swizzle: col' = col ^ (row<<2), 8B-block granular, bijective in-row.
    auto loadB = [&](bf16x8 (&BH)[3], bf16x8 (&BL)[3], int ks) {
        const int sw  = m << 2;
        const int kb0 = (ks * 32 + q * 4) ^ sw;
        const int kb1 = (ks * 32 + q * 4 + 16) ^ sw;
        #pragma unroll
        for (int ch = 0; ch < 3; ++ch) {
            const bf16x4 h0 = *(const bf16x4*)&Hls[ch * 2    ][m][kb0];
            const bf16x4 h1 = *(const bf16x4*)&Hls[ch * 2    ][m][kb1];
            const bf16x4 l0 = *(const bf16x4*)&Hls[ch * 2 + 1][m][kb0];
            const bf16x4 l1 = *(const bf16x4*)&Hls[ch * 2 + 1][m][kb1];
            BH[ch] = __builtin_shufflevector(h0, h1, 0, 1, 2, 3, 4, 5, 6, 7);
            BL[ch] = __builtin_shufflevector(l0, l1, 0, 1, 2, 3, 4, 5, 6, 7);
        }
    };
    auto mfma36 = [&](const bf16x8 (&AH)[4], const bf16x8 (&AL)[4],
                      const bf16x8 (&BH)[3], const bf16x8 (&BL)[3]) {
        __builtin_amdgcn_s_setprio(1);
        #pragma unroll
        for (int ch = 0; ch < 3; ++ch)
            #pragma unroll
            for (int nt = 0; nt < 4; ++nt)
                acc[ch][nt] = __builtin_amdgcn_mfma_f32_16x16x32_bf16(AH[nt], BH[ch], acc[ch][nt], 0, 0, 0);
        #pragma unroll
        for (int ch = 0; ch < 3; ++ch)
            #pragma unroll
            for (int nt = 0; nt < 4; ++nt)
                acc[ch][nt] = __builtin_amdgcn_mfma_f32_16x16x32_bf16(AH[nt], BL[ch], acc[ch][nt], 0, 0, 0);
        #pragma unroll
        for (int ch = 0; ch < 3; ++ch)
            #pragma unroll
            for (int nt = 0; nt < 4; ++nt)
                acc[ch][nt] = __builtin_amdgcn_mfma_f32_16x16x32_bf16(AL[nt], BH[ch], acc[ch][nt], 0, 0, 0);
        __builtin_amdgcn_s_setprio(0);
    };
    // 9 MFMAs: one A-frag x 3 channels x 3 split terms; no setprio (we WANT
    // VALU interleave in the transition).
    auto mfma9 = [&](const bf16x8& aH, const bf16x8& aL,
                     const bf16x8 (&bh)[3], const bf16x8 (&bl)[3],
                     f32x4& c0, f32x4& c1, f32x4& c2) {
        c0 = __builtin_amdgcn_mfma_f32_16x16x32_bf16(aH, bh[0], c0, 0, 0, 0);
        c1 = __builtin_amdgcn_mfma_f32_16x16x32_bf16(aH, bh[1], c1, 0, 0, 0);
        c2 = __builtin_amdgcn_mfma_f32_16x16x32_bf16(aH, bh[2], c2, 0, 0, 0);
        c0 = __builtin_amdgcn_mfma_f32_16x16x32_bf16(aH, bl[0], c0, 0, 0, 0);
        c1 = __builtin_amdgcn_mfma_f32_16x16x32_bf16(aH, bl[1], c1, 0, 0, 0);
        c2 = __builtin_amdgcn_mfma_f32_16x16x32_bf16(aH, bl[2], c2, 0, 0, 0);
        c0 = __builtin_amdgcn_mfma_f32_16x16x32_bf16(aL, bh[0], c0, 0, 0, 0);
        c1 = __builtin_amdgcn_mfma_f32_16x16x32_bf16(aL, bh[1], c1, 0, 0, 0);
        c2 = __builtin_amdgcn_mfma_f32_16x16x32_bf16(aL, bh[2], c2, 0, 0, 0);
    };
    auto storeP = [&](const bf16x8 (&PH)[3], const bf16x8 (&PL)[3], int c) {
        const int sw = m << 2;
        const int k0 = (wv * 64 + c * 32 + q * 4) ^ sw;
        const int k1 = (wv * 64 + c * 32 + q * 4 + 16) ^ sw;
        #pragma unroll
        for (int ch = 0; ch < 3; ++ch) {
            *(bf16x4*)&Hls[ch * 2    ][m][k0] = __builtin_shufflevector(PH[ch], PH[ch], 0, 1, 2, 3);
            *(bf16x4*)&Hls[ch * 2 + 1][m][k0] = __builtin_shufflevector(PL[ch], PL[ch], 0, 1, 2, 3);
            *(bf16x4*)&Hls[ch * 2    ][m][k1] = __builtin_shufflevector(PH[ch], PH[ch], 4, 5, 6, 7);
            *(bf16x4*)&Hls[ch * 2 + 1][m][k1] = __builtin_shufflevector(PL[ch], PL[ch], 4, 5, 6, 7);
        }
    };

    // ---- layer 0: thread -> point p = tid&15, cols cg..cg+15 ----
    {
        const int p  = tid & 15;
        const int cg = (tid >> 4) * 16;
        const float xv = xe[pb + p];
        float vv[16], dd[16], ss[16];
        #pragma unroll
        for (int cc = 0; cc < 16; ++cc) {
            const int c = cg + cc;
            const float w  = W0[c];
            const float bb = b0[c];
            const float v  = fast_tanh(fmaf(xv, w, bb));
            const float s2 = 1.0f - v * v;
            vv[cc] = v;
            dd[cc] = s2 * w;
            ss[cc] = -2.0f * v * s2 * w * w;
        }
        auto packwrite = [&](const float (&a)[16], int cp) {
            #pragma unroll
            for (int g = 0; g < 4; ++g) {
                bf16x4 h, lo;
                #pragma unroll
                for (int e = 0; e < 4; ++e) {
                    const float fv = a[g * 4 + e];
                    const __bf16 hh = (__bf16)fv;
                    h[e]  = hh;
                    lo[e] = (__bf16)(fv - (float)hh);
                }
                const int col = (cg + g * 4) ^ (p << 2);
                *(bf16x4*)&Hls[cp    ][p][col] = h;
                *(bf16x4*)&Hls[cp + 1][p][col] = lo;
            }
        };
        packwrite(vv, 0);
        packwrite(dd, 2);
        packwrite(ss, 4);
    }
    __syncthreads();

    // ---- GEMM layer 1 (W1): all 8 K-chunks from LDS, dbuf pipeline ----
    zacc();
    loadA(AH0, AL0, Wh, Wl, 0);
    loadB(BH0, BL0, 0);
    #pragma unroll 1
    for (int it = 0; it < 4; ++it) {
        const int ks = it * 2;
        loadA(AH1, AL1, Wh, Wl, ks + 1);
        loadB(BH1, BL1, ks + 1);
        mfma36(AH0, AL0, BH0, BL0);
        if (it < 3) {
            loadA(AH0, AL0, Wh, Wl, ks + 2);
            loadB(BH0, BL0, ks + 2);
        }
        mfma36(AH1, AL1, BH1, BL1);
    }

    // ---- transitions: drain -> (epi c0 | store | own-mfma) x2 -> publish ----
    #pragma unroll 1
    for (int l = 0; l < 2; ++l) {
        const __bf16* whN = Wh + (l + 1) * (HID * HID);
        const __bf16* wlN = Wl + (l + 1) * (HID * HID);
        const float* bl = (l == 0) ? b1 : b2;

        __syncthreads();   // read-drain: all waves done reading H(l)
        loadA(AH0, AL0, whN, wlN, 2 * wv);         // own-chunk A frags (L2)
        loadA(AH1, AL1, whN, wlN, 2 * wv + 1);

        bf16x8 P0H[3], P0L[3], P1H[3], P1L[3];

        // ---- epilogue half c = 0 (nt 0,1) ----
        #pragma unroll
        for (int t = 0; t < 2; ++t)
            #pragma unroll
            for (int r = 0; r < 4; ++r) {
                const int nt = t;
                const int n  = (wv * 4 + nt) * 16 + q * 4 + r;
                const float zv = acc[0][nt][r] + bl[n];
                const float zd = acc[1][nt][r];
                const float zs = acc[2][nt][r];
                const float v  = fast_tanh(zv);
                const float s2 = 1.0f - v * v;
                const float dn = s2 * zd;
                const float sn = s2 * zs - 2.0f * v * s2 * zd * zd;
                const int e = t * 4 + r;
                { const __bf16 h = (__bf16)v;  P0H[0][e] = h; P0L[0][e] = (__bf16)(v  - (float)h); }
                { const __bf16 h = (__bf16)dn; P0H[1][e] = h; P0L[1][e] = (__bf16)(dn - (float)h); }
                { const __bf16 h = (__bf16)sn; P0H[2][e] = h; P0L[2][e] = (__bf16)(sn - (float)h); }
            }
        storeP(P0H, P0L, 0);                       // DS pipe, overlaps c=1 VALU
        #pragma unroll
        for (int ch = 0; ch < 3; ++ch) { acc[ch][0] = (f32x4)0.0f; acc[ch][1] = (f32x4)0.0f; }
        mfma9(AH0[0], AL0[0], P0H, P0L, acc[0][0], acc[1][0], acc[2][0]);   // own chunk 2wv, nt0
        mfma9(AH0[1], AL0[1], P0H, P0L, acc[0][1], acc[1][1], acc[2][1]);   // own chunk 2wv, nt1

        // ---- epilogue half c = 1 (nt 2,3) — interleaves with MFMAs above ----
        #pragma unroll
        for (int t = 0; t < 2; ++t)
            #pragma unroll
            for (int r = 0; r < 4; ++r) {
                const int nt = 2 + t;
                const int n  = (wv * 4 + nt) * 16 + q * 4 + r;
                const float zv = acc[0][nt][r] + bl[n];
                const float zd = acc[1][nt][r];
                const float zs = acc[2][nt][r];
                const float v  = fast_tanh(zv);
                const float s2 = 1.0f - v * v;
                const float dn = s2 * zd;
                const float sn = s2 * zs - 2.0f * v * s2 * zd * zd;
                const int e = t * 4 + r;
                { const __bf16 h = (__bf16)v;  P1H[0][e] = h; P1L[0][e] = (__bf16)(v  - (float)h); }
                { const __bf16 h = (__bf16)dn; P1H[1][e] = h; P1L[1][e] = (__bf16)(dn - (float)h); }
                { const __bf16 h = (__bf16)sn; P1H[2][e] = h; P1L[2][e] = (__bf16)(sn - (float)h); }
            }
        storeP(P1H, P1L, 1);
        #pragma unroll
        for (int ch = 0; ch < 3; ++ch) { acc[ch][2] = (f32x4)0.0f; acc[ch][3] = (f32x4)0.0f; }
        mfma9(AH0[2], AL0[2], P0H, P0L, acc[0][2], acc[1][2], acc[2][2]);   // own chunk 2wv, nt2
        mfma9(AH0[3], AL0[3], P0H, P0L, acc[0][3], acc[1][3], acc[2][3]);   // own chunk 2wv, nt3
        mfma9(AH1[0], AL1[0], P1H, P1L, acc[0][0], acc[1][0], acc[2][0]);   // own chunk 2wv+1
        mfma9(AH1[1], AL1[1], P1H, P1L, acc[0][1], acc[1][1], acc[2][1]);
        mfma9(AH1[2], AL1[2], P1H, P1L, acc[0][2], acc[1][2], acc[2][2]);
        mfma9(AH1[3], AL1[3], P1H, P1L, acc[0][3], acc[1][3], acc[2][3]);

        loadA(AH0, AL0, whN, wlN, (2 * wv + 2) & 7);   // prefetch first LDS chunk's A
        __syncthreads();   // publish H(l+1)
        loadB(BH0, BL0, (2 * wv + 2) & 7);
        #pragma unroll 1
        for (int it = 0; it < 3; ++it) {
            const int kb = (2 * wv + 3 + 2 * it) & 7;
            loadA(AH1, AL1, whN, wlN, kb);
            loadB(BH1, BL1, kb);
            mfma36(AH0, AL0, BH0, BL0);
            if (it < 2) {
                const int kc = (2 * wv + 4 + 2 * it) & 7;
                loadA(AH0, AL0, whN, wlN, kc);
                loadB(BH0, BL0, kc);
            }
            mfma36(AH1, AL1, BH1, BL1);
        }
    }

    // ---- layer 3 finish: s-channel register-direct into W4 dot ----
    {
        float P = 0.0f;
        #pragma unroll
        for (int nt = 0; nt < 4; ++nt)
            #pragma unroll
            for (int r = 0; r < 4; ++r) {
                const int n  = (wv * 4 + nt) * 16 + q * 4 + r;
                const float zv = acc[0][nt][r] + b3[n];
                const float zd = acc[1][nt][r];
                const float zs = acc[2][nt][r];
                const float v  = fast_tanh(zv);
                const float s2 = 1.0f - v * v;
                const float sn = s2 * zs - 2.0f * v * s2 * zd * zd;
                P = fmaf(sn, W4[n], P);
            }
        P += __shfl_xor(P, 16, 64);
        P += __shfl_xor(P, 32, 64);
        __syncthreads();   // all Hls reads done everywhere; red may alias Hls
        if (q == 0) red[wv][m] = P;
        __syncthreads();
        if (tid < 16)
            out[pb + tid] = red[0][tid] + red[1][tid] + red[2][tid] + red[3][tid];
    }
}

extern "C" void kernel_launch(void* const* d_in, const int* in_sizes, int n_in,
                              void* d_out, int out_size, void* d_ws, size_t ws_size,
                              hipStream_t stream) {
    const float* xe = (const float*)d_in[0];
    const float* xb = (const float*)d_in[1];
    const float* W0 = (const float*)d_in[2];
    const float* b0 = (const float*)d_in[3];
    const float* W1 = (const float*)d_in[4];
    const float* b1 = (const float*)d_in[5];
    const float* W2 = (const float*)d_in[6];
    const float* b2 = (const float*)d_in[7];
    const float* W3 = (const float*)d_in[8];
    const float* b3 = (const float*)d_in[9];
    const float* W4 = (const float*)d_in[10];
    const float* b4 = (const float*)d_in[11];
    float* out = (float*)d_out;

    const int n_eq = in_sizes[0];   // 262144
    const int n_b  = in_sizes[1];   // 8192

    __bf16* Wh = (__bf16*)d_ws;                    // 3*256*256 bf16
    __bf16* Wl = Wh + WELEM;

    const int neqb = n_eq / MPTS;                  // 16384
    const int nbb  = n_b / 16;                     // 512

    prep_w<<<WELEM / 256, 256, 0, stream>>>(W1, W2, W3, Wh, Wl);

    pinn_fused<<<neqb + nbb, 256, 0, stream>>>(
        xe, xb, W0, b0, b1, b2, b3, W4, b4, W1, W2, W3, Wh, Wl, out, neqb, n_eq);
}

// Round 6
// 998.724 us; speedup vs baseline: 2.3766x; 1.0004x over previous
//
#include <hip/hip_runtime.h>

// PoissonPinn, round-9: halve L2 weight bandwidth via MPTS=32 (512-thread blocks).
//
// Round-8 post-mortem: three schedules all pin MfmaUtil at 46-50% -> resource
// limit, not ordering. Arithmetic: each block re-reads all of Wh+Wl per layer
// -> 12.6 GB L2 traffic/dispatch = ~80% of per-XCD L2 BW; queueing-inflated
// L2 latency starves MFMA (flat 47% regardless of schedule). MFMA floor ~447us.
//
// Round-9: MPTS 16->32, 512 threads (8 waves). Each weight fragment feeds TWO
// point-tiles -> weight traffic halves (6.3 GB, ~40% of L2 ceiling). Per-wave
// MFMA count, per-thread VALU, acc registers all unchanged (reshaped 2NTx2PT).
// LDS 96 KB dynamic -> 1 block/CU, 8 waves = same 2 waves/SIMD as before.
// Own-chunk: wave wv's epilogue output IS chunk ks=wv's B-frag (j=4t+r);
// 8 waves cover all 8 chunks; 36 register-direct MFMAs per transition.

constexpr int HID   = 256;
constexpr int MPTS  = 32;              // points per eq block (two 16-wide p-tiles)
constexpr int SK    = 256;             // LDS row stride in bf16 elems (512B)
constexpr int WELEM = 3 * HID * HID;
constexpr int HLSB  = 6 * MPTS * SK * 2;   // 98304 B = 96 KiB

typedef __bf16 bf16x8 __attribute__((ext_vector_type(8)));
typedef __bf16 bf16x4 __attribute__((ext_vector_type(4)));
typedef float  f32x4  __attribute__((ext_vector_type(4)));

__device__ __forceinline__ float fast_tanh(float x) {
    float e = __expf(2.0f * x);
    return 1.0f - 2.0f / (e + 1.0f);
}

// ---- prep: W1..W3 (fp32 [k][n]) -> bf16 hi/lo, A-fragment order.
// Layout Wf[l][NT(16)][ks(8)][lane(64)][j(8)]: lane = q*16+m supplies
// A[n = NT*16+m][slot j] = W[k][n] with k = 32*ks + 16*(j>>2) + 4*q + (j&3).
__global__ void prep_w(const float* __restrict__ W1,
                       const float* __restrict__ W2,
                       const float* __restrict__ W3,
                       __bf16* __restrict__ Wh, __bf16* __restrict__ Wl) {
    const int idx = blockIdx.x * 256 + threadIdx.x;   // 0 .. WELEM-1
    const int l   = idx >> 16;
    const int r   = idx & 0xFFFF;
    const int NT  = r >> 12;
    const int ks  = (r >> 9) & 7;
    const int ln  = (r >> 3) & 63;
    const int j   = r & 7;
    const int q   = ln >> 4;
    const int mm  = ln & 15;
    const int k   = ks * 32 + ((j >> 2) << 4) + q * 4 + (j & 3);
    const int n   = NT * 16 + mm;
    const float* W = (l == 0) ? W1 : (l == 1) ? W2 : W3;
    const float w  = W[k * HID + n];
    const __bf16 hi = (__bf16)w;
    Wh[idx] = hi;
    Wl[idx] = (__bf16)(w - (float)hi);
}

__global__ __launch_bounds__(512, 2)
void pinn_fused(const float* __restrict__ xe, const float* __restrict__ xb,
                const float* __restrict__ W0, const float* __restrict__ b0,
                const float* __restrict__ b1, const float* __restrict__ b2,
                const float* __restrict__ b3, const float* __restrict__ W4,
                const float* __restrict__ b4,
                const float* __restrict__ W1f, const float* __restrict__ W2f,
                const float* __restrict__ W3f,
                const __bf16* __restrict__ Wh, const __bf16* __restrict__ Wl,
                float* __restrict__ out, int neqb, int n_eq)
{
    extern __shared__ __align__(16) unsigned char smem[];

    const int tid  = threadIdx.x;
    const int lane = tid & 63;
    const int wv   = tid >> 6;          // 0..7

    if ((int)blockIdx.x >= neqb) {
        // ================= boundary path (fp32 vector forward, 32 pts) =====
        float (*HV)[HID] = (float (*)[HID])smem;     // 32 KB of the 96
        const int rbase = wv * 4;                    // 0..28
        const int pbase = ((int)blockIdx.x - neqb) * 32 + rbase;
        float* bout = out + n_eq;

        #pragma unroll
        for (int c = 0; c < 4; ++c) {
            const int   j  = lane + 64 * c;
            const float w  = W0[j];
            const float bb = b0[j];
            #pragma unroll
            for (int p = 0; p < 4; ++p)
                HV[rbase + p][j] = fast_tanh(xb[pbase + p] * w + bb);
        }
        __syncthreads();

        const float* Ws[3] = {W1f, W2f, W3f};
        const float* bs[3] = {b1, b2, b3};

        #pragma unroll
        for (int l = 0; l < 3; ++l) {
            const float* __restrict__ W = Ws[l];
            const float* __restrict__ b = bs[l];

            float zv[4][4];
            #pragma unroll
            for (int p = 0; p < 4; ++p)
                #pragma unroll
                for (int c = 0; c < 4; ++c)
                    zv[p][c] = b[lane + 64 * c];

            for (int i = 0; i < HID; i += 4) {
                float w[4][4];
                #pragma unroll
                for (int qq = 0; qq < 4; ++qq)
                    #pragma unroll
                    for (int c = 0; c < 4; ++c)
                        w[qq][c] = W[(i + qq) * HID + lane + 64 * c];

                #pragma unroll
                for (int p = 0; p < 4; ++p) {
                    const float4 av = *(const float4*)&HV[rbase + p][i];
                    #pragma unroll
                    for (int qq = 0; qq < 4; ++qq) {
                        const float a_v = ((const float*)&av)[qq];
                        #pragma unroll
                        for (int c = 0; c < 4; ++c)
                            zv[p][c] = fmaf(a_v, w[qq][c], zv[p][c]);
                    }
                }
            }
            __syncthreads();

            #pragma unroll
            for (int p = 0; p < 4; ++p)
                #pragma unroll
                for (int c = 0; c < 4; ++c)
                    HV[rbase + p][lane + 64 * c] = fast_tanh(zv[p][c]);
            __syncthreads();
        }

        const float bias4 = b4[0];
        #pragma unroll
        for (int p = 0; p < 4; ++p) {
            float acc = 0.0f;
            #pragma unroll
            for (int c = 0; c < 4; ++c) {
                const int j = lane + 64 * c;
                acc = fmaf(HV[rbase + p][j], W4[j], acc);
            }
            #pragma unroll
            for (int off = 32; off > 0; off >>= 1)
                acc += __shfl_down(acc, off, 64);
            if (lane == 0) bout[pbase + p] = acc + bias4;
        }
        return;
    }

    // ================= equation path (2nd-order jet, MFMA) =================
    typedef __bf16 (*HlsT)[MPTS][SK];
    HlsT Hls = (HlsT)smem;                               // [6][32][256]
    float* redf = (float*)smem;                          // aliased (guarded)

    const int m    = lane & 15;     // B-frag col within p-tile
    const int q    = lane >> 4;
    const int pb   = blockIdx.x * MPTS;

    f32x4 acc[3][2][2];                            // [ch][t][pt]
    bf16x8 AH0[2], AL0[2], AH1[2], AL1[2];         // weight frags (dbuf): t=0,1
    bf16x8 BH0[2][3], BL0[2][3], BH1[2][3], BL1[2][3];   // act frags [pt][ch]

    auto zacc = [&]() {
        #pragma unroll
        for (int ch = 0; ch < 3; ++ch)
            #pragma unroll
            for (int t = 0; t < 2; ++t)
                #pragma unroll
                for (int pt = 0; pt < 2; ++pt)
                    acc[ch][t][pt] = (f32x4)0.0f;
    };
    auto loadA = [&](bf16x8 (&AH)[2], bf16x8 (&AL)[2],
                     const __bf16* wh, const __bf16* wl, int ks) {
        #pragma unroll
        for (int t = 0; t < 2; ++t) {
            const int off = (((2 * wv + t) * 8 + ks) * 64 + lane) * 8;
            AH[t] = *(const bf16x8*)(wh + off);
            AL[t] = *(const bf16x8*)(wl + off);
        }
    };
    // XOR swizzle: col' = col ^ ((row&15)<<2), 8B-block granular.
    auto loadB = [&](bf16x8 (&BH)[2][3], bf16x8 (&BL)[2][3], int ks) {
        const int sw  = m << 2;
        const int kb0 = (ks * 32 + q * 4) ^ sw;
        const int kb1 = (ks * 32 + q * 4 + 16) ^ sw;
        #pragma unroll
        for (int pt = 0; pt < 2; ++pt) {
            const int row = pt * 16 + m;
            #pragma unroll
            for (int ch = 0; ch < 3; ++ch) {
                const bf16x4 h0 = *(const bf16x4*)&Hls[ch * 2    ][row][kb0];
                const bf16x4 h1 = *(const bf16x4*)&Hls[ch * 2    ][row][kb1];
                const bf16x4 l0 = *(const bf16x4*)&Hls[ch * 2 + 1][row][kb0];
                const bf16x4 l1 = *(const bf16x4*)&Hls[ch * 2 + 1][row][kb1];
                BH[pt][ch] = __builtin_shufflevector(h0, h1, 0, 1, 2, 3, 4, 5, 6, 7);
                BL[pt][ch] = __builtin_shufflevector(l0, l1, 0, 1, 2, 3, 4, 5, 6, 7);
            }
        }
    };
    // 36 MFMAs per K-chunk: 2t x 2pt x 3ch x 3 split terms, term-major.
    auto mfmaChunk = [&](const bf16x8 (&AH)[2], const bf16x8 (&AL)[2],
                         const bf16x8 (&BH)[2][3], const bf16x8 (&BL)[2][3]) {
        __builtin_amdgcn_s_setprio(1);
        #pragma unroll
        for (int pt = 0; pt < 2; ++pt)
            #pragma unroll
            for (int ch = 0; ch < 3; ++ch)
                #pragma unroll
                for (int t = 0; t < 2; ++t)
                    acc[ch][t][pt] = __builtin_amdgcn_mfma_f32_16x16x32_bf16(AH[t], BH[pt][ch], acc[ch][t][pt], 0, 0, 0);
        #pragma unroll
        for (int pt = 0; pt < 2; ++pt)
            #pragma unroll
            for (int ch = 0; ch < 3; ++ch)
                #pragma unroll
                for (int t = 0; t < 2; ++t)
                    acc[ch][t][pt] = __builtin_amdgcn_mfma_f32_16x16x32_bf16(AH[t], BL[pt][ch], acc[ch][t][pt], 0, 0, 0);
        #pragma unroll
        for (int pt = 0; pt < 2; ++pt)
            #pragma unroll
            for (int ch = 0; ch < 3; ++ch)
                #pragma unroll
                for (int t = 0; t < 2; ++t)
                    acc[ch][t][pt] = __builtin_amdgcn_mfma_f32_16x16x32_bf16(AL[t], BH[pt][ch], acc[ch][t][pt], 0, 0, 0);
        __builtin_amdgcn_s_setprio(0);
    };

    // ---- layer 0: thread -> point p = tid&31, cols cg..cg+15 ----
    {
        const int p  = tid & 31;
        const int cg = (tid >> 5) * 16;
        const float xv = xe[pb + p];
        float vv[16], dd[16], ss[16];
        #pragma unroll
        for (int cc = 0; cc < 16; ++cc) {
            const int c = cg + cc;
            const float w  = W0[c];
            const float bb = b0[c];
            const float v  = fast_tanh(fmaf(xv, w, bb));
            const float s2 = 1.0f - v * v;
            vv[cc] = v;
            dd[cc] = s2 * w;
            ss[cc] = -2.0f * v * s2 * w * w;
        }
        auto packwrite = [&](const float (&a)[16], int cp) {
            #pragma unroll
            for (int g = 0; g < 4; ++g) {
                bf16x4 h, lo;
                #pragma unroll
                for (int e = 0; e < 4; ++e) {
                    const float fv = a[g * 4 + e];
                    const __bf16 hh = (__bf16)fv;
                    h[e]  = hh;
                    lo[e] = (__bf16)(fv - (float)hh);
                }
                const int col = (cg + g * 4) ^ ((p & 15) << 2);
                *(bf16x4*)&Hls[cp    ][p][col] = h;
                *(bf16x4*)&Hls[cp + 1][p][col] = lo;
            }
        };
        packwrite(vv, 0);
        packwrite(dd, 2);
        packwrite(ss, 4);
    }
    __syncthreads();

    // ---- GEMM layer 1 (W1): 8 K-chunks from LDS, dbuf pipeline ----
    zacc();
    loadA(AH0, AL0, Wh, Wl, 0);
    loadB(BH0, BL0, 0);
    #pragma unroll 1
    for (int it = 0; it < 4; ++it) {
        const int ks = it * 2;
        loadA(AH1, AL1, Wh, Wl, ks + 1);
        loadB(BH1, BL1, ks + 1);
        mfmaChunk(AH0, AL0, BH0, BL0);
        if (it < 3) {
            loadA(AH0, AL0, Wh, Wl, ks + 2);
            loadB(BH0, BL0, ks + 2);
        }
        mfmaChunk(AH1, AL1, BH1, BL1);
    }

    // ---- transitions: drain -> per-pt {epi | store | own-chunk mfma} -> publish ----
    #pragma unroll 1
    for (int l = 0; l < 2; ++l) {
        const __bf16* whN = Wh + (l + 1) * (HID * HID);
        const __bf16* wlN = Wl + (l + 1) * (HID * HID);
        const float* bl = (l == 0) ? b1 : b2;

        __syncthreads();   // drain: all waves done reading H(l)
        loadA(AH1, AL1, whN, wlN, wv);              // own chunk ks=wv
        loadA(AH0, AL0, whN, wlN, (wv + 1) & 7);    // first LDS chunk prefetch

        bf16x8 PH[2][3], PL[2][3];
        #pragma unroll
        for (int pt = 0; pt < 2; ++pt) {
            // epilogue half for p-tile pt (VALU)
            #pragma unroll
            for (int t = 0; t < 2; ++t)
                #pragma unroll
                for (int r = 0; r < 4; ++r) {
                    const int n  = 32 * wv + 16 * t + 4 * q + r;
                    const float zv = acc[0][t][pt][r] + bl[n];
                    const float zd = acc[1][t][pt][r];
                    const float zs = acc[2][t][pt][r];
                    const float v  = fast_tanh(zv);
                    const float s2 = 1.0f - v * v;
                    const float dn = s2 * zd;
                    const float sn = s2 * zs - 2.0f * v * s2 * zd * zd;
                    const int e = t * 4 + r;
                    { const __bf16 h = (__bf16)v;  PH[pt][0][e] = h; PL[pt][0][e] = (__bf16)(v  - (float)h); }
                    { const __bf16 h = (__bf16)dn; PH[pt][1][e] = h; PL[pt][1][e] = (__bf16)(dn - (float)h); }
                    { const __bf16 h = (__bf16)sn; PH[pt][2][e] = h; PL[pt][2][e] = (__bf16)(sn - (float)h); }
                }
            // exchange-write own 32-col k-slice for this p-tile (DS pipe)
            {
                const int sw  = m << 2;
                const int row = pt * 16 + m;
                const int k0  = (32 * wv + 4 * q) ^ sw;
                const int k1  = (32 * wv + 16 + 4 * q) ^ sw;
                #pragma unroll
                for (int ch = 0; ch < 3; ++ch) {
                    *(bf16x4*)&Hls[ch * 2    ][row][k0] = __builtin_shufflevector(PH[pt][ch], PH[pt][ch], 0, 1, 2, 3);
                    *(bf16x4*)&Hls[ch * 2 + 1][row][k0] = __builtin_shufflevector(PL[pt][ch], PL[pt][ch], 0, 1, 2, 3);
                    *(bf16x4*)&Hls[ch * 2    ][row][k1] = __builtin_shufflevector(PH[pt][ch], PH[pt][ch], 4, 5, 6, 7);
                    *(bf16x4*)&Hls[ch * 2 + 1][row][k1] = __builtin_shufflevector(PL[pt][ch], PL[pt][ch], 4, 5, 6, 7);
                }
            }
            // own-chunk MFMAs for this p-tile (18): register-direct B
            #pragma unroll
            for (int ch = 0; ch < 3; ++ch)
                #pragma unroll
                for (int t = 0; t < 2; ++t)
                    acc[ch][t][pt] = (f32x4)0.0f;
            #pragma unroll
            for (int ch = 0; ch < 3; ++ch)
                #pragma unroll
                for (int t = 0; t < 2; ++t)
                    acc[ch][t][pt] = __builtin_amdgcn_mfma_f32_16x16x32_bf16(AH1[t], PH[pt][ch], acc[ch][t][pt], 0, 0, 0);
            #pragma unroll
            for (int ch = 0; ch < 3; ++ch)
                #pragma unroll
                for (int t = 0; t < 2; ++t)
                    acc[ch][t][pt] = __builtin_amdgcn_mfma_f32_16x16x32_bf16(AH1[t], PL[pt][ch], acc[ch][t][pt], 0, 0, 0);
            #pragma unroll
            for (int ch = 0; ch < 3; ++ch)
                #pragma unroll
                for (int t = 0; t < 2; ++t)
                    acc[ch][t][pt] = __builtin_amdgcn_mfma_f32_16x16x32_bf16(AL1[t], PH[pt][ch], acc[ch][t][pt], 0, 0, 0);
        }

        __syncthreads();   // publish H(l+1)
        loadB(BH0, BL0, (wv + 1) & 7);
        #pragma unroll 1
        for (int it = 0; it < 3; ++it) {
            const int kn1 = (wv + 2 + 2 * it) & 7;
            loadA(AH1, AL1, whN, wlN, kn1);
            loadB(BH1, BL1, kn1);
            mfmaChunk(AH0, AL0, BH0, BL0);
            const int kn2 = (wv + 3 + 2 * it) & 7;
            loadA(AH0, AL0, whN, wlN, kn2);
            loadB(BH0, BL0, kn2);
            mfmaChunk(AH1, AL1, BH1, BL1);
        }
        mfmaChunk(AH0, AL0, BH0, BL0);   // 7th LDS chunk
    }

    // ---- layer 3 finish: s-channel register-direct into W4 dot ----
    {
        float Pv[2] = {0.0f, 0.0f};
        #pragma unroll
        for (int pt = 0; pt < 2; ++pt)
            #pragma unroll
            for (int t = 0; t < 2; ++t)
                #pragma unroll
                for (int r = 0; r < 4; ++r) {
                    const int n  = 32 * wv + 16 * t + 4 * q + r;
                    const float zv = acc[0][t][pt][r] + b3[n];
                    const float zd = acc[1][t][pt][r];
                    const float zs = acc[2][t][pt][r];
                    const float v  = fast_tanh(zv);
                    const float s2 = 1.0f - v * v;
                    const float sn = s2 * zs - 2.0f * v * s2 * zd * zd;
                    Pv[pt] = fmaf(sn, W4[n], Pv[pt]);
                }
        #pragma unroll
        for (int pt = 0; pt < 2; ++pt) {
            Pv[pt] += __shfl_xor(Pv[pt], 16, 64);
            Pv[pt] += __shfl_xor(Pv[pt], 32, 64);
        }
        __syncthreads();   // all Hls reads done; redf may alias Hls
        if (q == 0) {
            redf[wv * 32 + m]      = Pv[0];
            redf[wv * 32 + 16 + m] = Pv[1];
        }
        __syncthreads();
        if (tid < 32) {
            float s = 0.0f;
            #pragma unroll
            for (int w = 0; w < 8; ++w)
                s += redf[w * 32 + tid];
            out[pb + tid] = s;
        }
    }
}

extern "C" void kernel_launch(void* const* d_in, const int* in_sizes, int n_in,
                              void* d_out, int out_size, void* d_ws, size_t ws_size,
                              hipStream_t stream) {
    const float* xe = (const float*)d_in[0];
    const float* xb = (const float*)d_in[1];
    const float* W0 = (const float*)d_in[2];
    const float* b0 = (const float*)d_in[3];
    const float* W1 = (const float*)d_in[4];
    const float* b1 = (const float*)d_in[5];
    const float* W2 = (const float*)d_in[6];
    const float* b2 = (const float*)d_in[7];
    const float* W3 = (const float*)d_in[8];
    const float* b3 = (const float*)d_in[9];
    const float* W4 = (const float*)d_in[10];
    const float* b4 = (const float*)d_in[11];
    float* out = (float*)d_out;

    const int n_eq = in_sizes[0];   // 262144
    const int n_b  = in_sizes[1];   // 8192

    __bf16* Wh = (__bf16*)d_ws;                    // 3*256*256 bf16
    __bf16* Wl = Wh + WELEM;

    static bool attr_done = false;
    if (!attr_done) {
        hipFuncSetAttribute((const void*)pinn_fused,
                            hipFuncAttributeMaxDynamicSharedMemorySize, HLSB);
        attr_done = true;
    }

    const int neqb = n_eq / MPTS;                  // 8192
    const int nbb  = n_b / 32;                     // 256

    prep_w<<<WELEM / 256, 256, 0, stream>>>(W1, W2, W3, Wh, Wl);

    pinn_fused<<<neqb + nbb, 512, HLSB, stream>>>(
        xe, xb, W0, b0, b1, b2, b3, W4, b4, W1, W2, W3, Wh, Wl, out, neqb, n_eq);
}

// Round 8
// 947.841 us; speedup vs baseline: 2.5042x; 1.0537x over previous
//
#include <hip/hip_runtime.h>

// PoissonPinn, round-11: round-10 with the compile fix (pack2 by-value outputs;
// vector elements can't bind to non-const references).
//
// R10 package (unchanged):
//  * Truncation hi/lo split + pair packing (shift/and/or -> v_bfi): ~3 ops/val
//    vs ~10-12 for compiler RNE (__bf16) casts. Predicted absmax ~2.5e-4.
//  * Slot-contiguous LDS (col = 32ks+8q+4t+r): B-frag = ONE ds_read_b128;
//    storeP = 12 ds_write_b128. Bank safety via 528B row pad (33x16B):
//    per-quarter-wave 2 lanes/bank-quad = minimum. No XOR swizzle.
//  * Keeps R8: fused boundary, drain-before-epilogue, own-chunk register-direct
//    mfma36, (256,2).

constexpr int HID   = 256;
constexpr int MPTS  = 16;
constexpr int SKE   = 264;             // row stride elems (528 B)
constexpr int WELEM = 3 * HID * HID;
constexpr int HLSB  = 6 * MPTS * SKE * 2;   // 50688 B

typedef __bf16 bf16x8 __attribute__((ext_vector_type(8)));
typedef float  f32x4  __attribute__((ext_vector_type(4)));
typedef unsigned int u32x4 __attribute__((ext_vector_type(4)));
typedef unsigned int u32x2 __attribute__((ext_vector_type(2)));

__device__ __forceinline__ float fast_tanh(float x) {
    float e = __expf(2.0f * x);
    return 1.0f - 2.0f / (e + 1.0f);
}

struct packed2 { unsigned hi, lo; };

__device__ __forceinline__ packed2 pack2(float x, float y) {
    const unsigned xb = __float_as_uint(x), yb = __float_as_uint(y);
    const unsigned xh = xb & 0xFFFF0000u, yh = yb & 0xFFFF0000u;
    packed2 r;
    r.hi = (xb >> 16) | yh;
    const float dx = x - __uint_as_float(xh);
    const float dy = y - __uint_as_float(yh);
    r.lo = (__float_as_uint(dx) >> 16) | (__float_as_uint(dy) & 0xFFFF0000u);
    return r;
}

__global__ void prep_w(const float* __restrict__ W1,
                       const float* __restrict__ W2,
                       const float* __restrict__ W3,
                       __bf16* __restrict__ Wh, __bf16* __restrict__ Wl) {
    const int idx = blockIdx.x * 256 + threadIdx.x;
    const int l   = idx >> 16;
    const int r   = idx & 0xFFFF;
    const int NT  = r >> 12;
    const int ks  = (r >> 9) & 7;
    const int ln  = (r >> 3) & 63;
    const int j   = r & 7;
    const int q   = ln >> 4;
    const int mm  = ln & 15;
    const int k   = ks * 32 + ((j >> 2) << 4) + q * 4 + (j & 3);
    const int n   = NT * 16 + mm;
    const float* W = (l == 0) ? W1 : (l == 1) ? W2 : W3;
    const float w  = W[k * HID + n];
    const __bf16 hi = (__bf16)w;
    Wh[idx] = hi;
    Wl[idx] = (__bf16)(w - (float)hi);
}

__global__ __launch_bounds__(256, 2)
void pinn_fused(const float* __restrict__ xe, const float* __restrict__ xb,
                const float* __restrict__ W0, const float* __restrict__ b0,
                const float* __restrict__ b1, const float* __restrict__ b2,
                const float* __restrict__ b3, const float* __restrict__ W4,
                const float* __restrict__ b4,
                const float* __restrict__ W1f, const float* __restrict__ W2f,
                const float* __restrict__ W3f,
                const __bf16* __restrict__ Wh, const __bf16* __restrict__ Wl,
                float* __restrict__ out, int neqb, int n_eq)
{
    __shared__ __align__(16) unsigned char smem[HLSB];

    const int tid  = threadIdx.x;
    const int lane = tid & 63;
    const int wv   = tid >> 6;

    if ((int)blockIdx.x >= neqb) {
        // ================= boundary path =================
        float (*HV)[HID] = (float (*)[HID])smem;
        const int rbase = wv * 4;
        const int pbase = ((int)blockIdx.x - neqb) * 16 + rbase;
        float* bout = out + n_eq;

        #pragma unroll
        for (int c = 0; c < 4; ++c) {
            const int   j  = lane + 64 * c;
            const float w  = W0[j];
            const float bb = b0[j];
            #pragma unroll
            for (int p = 0; p < 4; ++p)
                HV[rbase + p][j] = fast_tanh(xb[pbase + p] * w + bb);
        }
        __syncthreads();

        const float* Ws[3] = {W1f, W2f, W3f};
        const float* bs[3] = {b1, b2, b3};

        #pragma unroll
        for (int l = 0; l < 3; ++l) {
            const float* __restrict__ W = Ws[l];
            const float* __restrict__ b = bs[l];

            float zv[4][4];
            #pragma unroll
            for (int p = 0; p < 4; ++p)
                #pragma unroll
                for (int c = 0; c < 4; ++c)
                    zv[p][c] = b[lane + 64 * c];

            for (int i = 0; i < HID; i += 4) {
                float w[4][4];
                #pragma unroll
                for (int qq = 0; qq < 4; ++qq)
                    #pragma unroll
                    for (int c = 0; c < 4; ++c)
                        w[qq][c] = W[(i + qq) * HID + lane + 64 * c];

                #pragma unroll
                for (int p = 0; p < 4; ++p) {
                    const float4 av = *(const float4*)&HV[rbase + p][i];
                    #pragma unroll
                    for (int qq = 0; qq < 4; ++qq) {
                        const float a_v = ((const float*)&av)[qq];
                        #pragma unroll
                        for (int c = 0; c < 4; ++c)
                            zv[p][c] = fmaf(a_v, w[qq][c], zv[p][c]);
                    }
                }
            }
            __syncthreads();

            #pragma unroll
            for (int p = 0; p < 4; ++p)
                #pragma unroll
                for (int c = 0; c < 4; ++c)
                    HV[rbase + p][lane + 64 * c] = fast_tanh(zv[p][c]);
            __syncthreads();
        }

        const float bias4 = b4[0];
        #pragma unroll
        for (int p = 0; p < 4; ++p) {
            float acc = 0.0f;
            #pragma unroll
            for (int c = 0; c < 4; ++c) {
                const int j = lane + 64 * c;
                acc = fmaf(HV[rbase + p][j], W4[j], acc);
            }
            #pragma unroll
            for (int off = 32; off > 0; off >>= 1)
                acc += __shfl_down(acc, off, 64);
            if (lane == 0) bout[pbase + p] = acc + bias4;
        }
        return;
    }

    // ================= equation path =================
    typedef __bf16 (*HlsT)[MPTS][SKE];
    HlsT Hls = (HlsT)smem;                               // [6][16][264]
    float (*red)[16] = (float (*)[16])smem;              // aliases Hls (guarded)

    const int m    = lane & 15;
    const int q    = lane >> 4;
    const int pb   = blockIdx.x * MPTS;

    f32x4 acc[3][4];                               // [ch][nt], nt = 2c+t
    bf16x8 AH0[4], AL0[4], AH1[4], AL1[4];
    u32x4  BH0[3], BL0[3], BH1[3], BL1[3];

    auto zacc = [&]() {
        #pragma unroll
        for (int ch = 0; ch < 3; ++ch)
            #pragma unroll
            for (int nt = 0; nt < 4; ++nt)
                acc[ch][nt] = (f32x4)0.0f;
    };
    auto loadA = [&](bf16x8 (&AH)[4], bf16x8 (&AL)[4],
                     const __bf16* wh, const __bf16* wl, int ks) {
        #pragma unroll
        for (int nt = 0; nt < 4; ++nt) {
            const int off = (((wv * 4 + nt) * 8 + ks) * 64 + lane) * 8;
            AH[nt] = *(const bf16x8*)(wh + off);
            AL[nt] = *(const bf16x8*)(wl + off);
        }
    };
    auto loadB = [&](u32x4 (&BH)[3], u32x4 (&BL)[3], int ks) {
        const int cb = ks * 32 + q * 8;
        #pragma unroll
        for (int ch = 0; ch < 3; ++ch) {
            BH[ch] = *(const u32x4*)&Hls[ch * 2    ][m][cb];
            BL[ch] = *(const u32x4*)&Hls[ch * 2 + 1][m][cb];
        }
    };
    auto MF = [&](const bf16x8& a, const u32x4& b, const f32x4& c) {
        return __builtin_amdgcn_mfma_f32_16x16x32_bf16(
            a, __builtin_bit_cast(bf16x8, b), c, 0, 0, 0);
    };
    auto mfma36 = [&](const bf16x8 (&AH)[4], const bf16x8 (&AL)[4],
                      const u32x4 (&BH)[3], const u32x4 (&BL)[3]) {
        __builtin_amdgcn_s_setprio(1);
        #pragma unroll
        for (int ch = 0; ch < 3; ++ch)
            #pragma unroll
            for (int nt = 0; nt < 4; ++nt)
                acc[ch][nt] = MF(AH[nt], BH[ch], acc[ch][nt]);
        #pragma unroll
        for (int ch = 0; ch < 3; ++ch)
            #pragma unroll
            for (int nt = 0; nt < 4; ++nt)
                acc[ch][nt] = MF(AH[nt], BL[ch], acc[ch][nt]);
        #pragma unroll
        for (int ch = 0; ch < 3; ++ch)
            #pragma unroll
            for (int nt = 0; nt < 4; ++nt)
                acc[ch][nt] = MF(AL[nt], BH[ch], acc[ch][nt]);
        __builtin_amdgcn_s_setprio(0);
    };

    // ---- layer 0 ----
    {
        const int p  = tid & 15;
        const int cg = (tid >> 4) * 16;
        const int ks = cg >> 5;
        const int t  = (cg >> 4) & 1;
        const float xv = xe[pb + p];
        float vv[16], dd[16], ss[16];
        #pragma unroll
        for (int cc = 0; cc < 16; ++cc) {
            const int c = cg + cc;
            const float w  = W0[c];
            const float bb = b0[c];
            const float v  = fast_tanh(fmaf(xv, w, bb));
            const float s2 = 1.0f - v * v;
            vv[cc] = v;
            dd[cc] = s2 * w;
            ss[cc] = -2.0f * v * s2 * w * w;
        }
        auto packwrite = [&](const float (&a)[16], int cp) {
            #pragma unroll
            for (int g = 0; g < 4; ++g) {
                const packed2 p0 = pack2(a[g * 4 + 0], a[g * 4 + 1]);
                const packed2 p1 = pack2(a[g * 4 + 2], a[g * 4 + 3]);
                u32x2 h, lo;
                h[0]  = p0.hi;  h[1]  = p1.hi;
                lo[0] = p0.lo;  lo[1] = p1.lo;
                const int col = 32 * ks + 8 * g + 4 * t;
                *(u32x2*)&Hls[cp    ][p][col] = h;
                *(u32x2*)&Hls[cp + 1][p][col] = lo;
            }
        };
        packwrite(vv, 0);
        packwrite(dd, 2);
        packwrite(ss, 4);
    }
    __syncthreads();

    // ---- layer 1 GEMM: 8 chunks ----
    zacc();
    loadA(AH0, AL0, Wh, Wl, 0);
    loadB(BH0, BL0, 0);
    #pragma unroll 1
    for (int it = 0; it < 4; ++it) {
        const int ks = it * 2;
        loadA(AH1, AL1, Wh, Wl, ks + 1);
        loadB(BH1, BL1, ks + 1);
        mfma36(AH0, AL0, BH0, BL0);
        if (it < 3) {
            loadA(AH0, AL0, Wh, Wl, ks + 2);
            loadB(BH0, BL0, ks + 2);
        }
        mfma36(AH1, AL1, BH1, BL1);
    }

    // ---- transitions ----
    #pragma unroll 1
    for (int l = 0; l < 2; ++l) {
        const __bf16* whN = Wh + (l + 1) * (HID * HID);
        const __bf16* wlN = Wl + (l + 1) * (HID * HID);
        const float* bl = (l == 0) ? b1 : b2;

        __syncthreads();   // drain: all waves done reading H(l)
        loadA(AH0, AL0, whN, wlN, 2 * wv);
        loadA(AH1, AL1, whN, wlN, 2 * wv + 1);

        u32x4 PH[3][2], PL[3][2];
        #pragma unroll
        for (int c = 0; c < 2; ++c)
            #pragma unroll
            for (int i = 0; i < 4; ++i) {
                const int t  = i >> 1;
                const int r0 = (i & 1) * 2;
                const int nt = c * 2 + t;
                float v2[2], d2[2], s2v[2];
                #pragma unroll
                for (int k = 0; k < 2; ++k) {
                    const int r = r0 + k;
                    const int n = 64 * wv + 32 * c + 16 * t + 4 * q + r;
                    const float zv = acc[0][nt][r] + bl[n];
                    const float zd = acc[1][nt][r];
                    const float zs = acc[2][nt][r];
                    const float v  = fast_tanh(zv);
                    const float s2 = 1.0f - v * v;
                    v2[k]  = v;
                    d2[k]  = s2 * zd;
                    s2v[k] = s2 * zs - 2.0f * v * s2 * zd * zd;
                }
                const packed2 pv = pack2(v2[0],  v2[1]);
                const packed2 pd = pack2(d2[0],  d2[1]);
                const packed2 ps = pack2(s2v[0], s2v[1]);
                PH[0][c][i] = pv.hi;  PL[0][c][i] = pv.lo;
                PH[1][c][i] = pd.hi;  PL[1][c][i] = pd.lo;
                PH[2][c][i] = ps.hi;  PL[2][c][i] = ps.lo;
            }

        // exchange store: 12 ds_write_b128 (drain under the own MFMAs below)
        #pragma unroll
        for (int c = 0; c < 2; ++c) {
            const int cb = (2 * wv + c) * 32 + q * 8;
            #pragma unroll
            for (int ch = 0; ch < 3; ++ch) {
                *(u32x4*)&Hls[ch * 2    ][m][cb] = PH[ch][c];
                *(u32x4*)&Hls[ch * 2 + 1][m][cb] = PL[ch][c];
            }
        }

        zacc();
        {
            u32x4 bh[3] = {PH[0][0], PH[1][0], PH[2][0]};
            u32x4 bo[3] = {PL[0][0], PL[1][0], PL[2][0]};
            mfma36(AH0, AL0, bh, bo);
        }
        {
            u32x4 bh[3] = {PH[0][1], PH[1][1], PH[2][1]};
            u32x4 bo[3] = {PL[0][1], PL[1][1], PL[2][1]};
            mfma36(AH1, AL1, bh, bo);
        }

        loadA(AH0, AL0, whN, wlN, (2 * wv + 2) & 7);
        __syncthreads();   // publish H(l+1)
        loadB(BH0, BL0, (2 * wv + 2) & 7);
        #pragma unroll 1
        for (int it = 0; it < 3; ++it) {
            const int kb = (2 * wv + 3 + 2 * it) & 7;
            loadA(AH1, AL1, whN, wlN, kb);
            loadB(BH1, BL1, kb);
            mfma36(AH0, AL0, BH0, BL0);
            if (it < 2) {
                const int kc = (2 * wv + 4 + 2 * it) & 7;
                loadA(AH0, AL0, whN, wlN, kc);
                loadB(BH0, BL0, kc);
            }
            mfma36(AH1, AL1, BH1, BL1);
        }
    }

    // ---- layer 3 finish: s-channel register-direct into W4 dot ----
    {
        float P = 0.0f;
        #pragma unroll
        for (int nt = 0; nt < 4; ++nt)
            #pragma unroll
            for (int r = 0; r < 4; ++r) {
                const int n  = (wv * 4 + nt) * 16 + q * 4 + r;
                const float zv = acc[0][nt][r] + b3[n];
                const float zd = acc[1][nt][r];
                const float zs = acc[2][nt][r];
                const float v  = fast_tanh(zv);
                const float s2 = 1.0f - v * v;
                const float sn = s2 * zs - 2.0f * v * s2 * zd * zd;
                P = fmaf(sn, W4[n], P);
            }
        P += __shfl_xor(P, 16, 64);
        P += __shfl_xor(P, 32, 64);
        __syncthreads();   // all Hls reads done; red may alias Hls
        if (q == 0) red[wv][m] = P;
        __syncthreads();
        if (tid < 16)
            out[pb + tid] = red[0][tid] + red[1][tid] + red[2][tid] + red[3][tid];
    }
}

extern "C" void kernel_launch(void* const* d_in, const int* in_sizes, int n_in,
                              void* d_out, int out_size, void* d_ws, size_t ws_size,
                              hipStream_t stream) {
    const float* xe = (const float*)d_in[0];
    const float* xb = (const float*)d_in[1];
    const float* W0 = (const float*)d_in[2];
    const float* b0 = (const float*)d_in[3];
    const float* W1 = (const float*)d_in[4];
    const float* b1 = (const float*)d_in[5];
    const float* W2 = (const float*)d_in[6];
    const float* b2 = (const float*)d_in[7];
    const float* W3 = (const float*)d_in[8];
    const float* b3 = (const float*)d_in[9];
    const float* W4 = (const float*)d_in[10];
    const float* b4 = (const float*)d_in[11];
    float* out = (float*)d_out;

    const int n_eq = in_sizes[0];   // 262144
    const int n_b  = in_sizes[1];   // 8192

    __bf16* Wh = (__bf16*)d_ws;
    __bf16* Wl = Wh + WELEM;

    const int neqb = n_eq / MPTS;                  // 16384
    const int nbb  = n_b / 16;                     // 512

    prep_w<<<WELEM / 256, 256, 0, stream>>>(W1, W2, W3, Wh, Wl);

    pinn_fused<<<neqb + nbb, 256, 0, stream>>>(
        xe, xb, W0, b0, b1, b2, b3, W4, b4, W1, W2, W3, Wh, Wl, out, neqb, n_eq);
}